// Round 1
// 414.909 us; speedup vs baseline: 1.0601x; 1.0601x over previous
//
#include <hip/hip_runtime.h>
#include <math.h>

// Problem constants
#define B_   4
#define S_   2048
#define D_   1024
#define H_   1024
#define NROW 2048
#define TOTX 8388608.0f            // B_*S_*D_ elements of x

typedef _Float16 f16x8 __attribute__((ext_vector_type(8)));
typedef float f32x4 __attribute__((ext_vector_type(4)));

__device__ __forceinline__ unsigned short f2h(float f) {
  _Float16 h = (_Float16)f;                       // v_cvt_f16_f32, RNE
  return __builtin_bit_cast(unsigned short, h);
}

// async global->LDS, 16B per lane, lands at ldsbase + lane*16
#define GLD16(gp, lp)                                                            \
  __builtin_amdgcn_global_load_lds(                                              \
      (__attribute__((address_space(1))) void*)(gp),                             \
      (__attribute__((address_space(3))) void*)(lp), 16, 0, 0)

// ---------------------------------------------------------------------------
// fused float->f16 conversion + abs-sum for x (one pass over 32 MB)
// ---------------------------------------------------------------------------
__global__ __launch_bounds__(256) void f2h_abs_kernel(const float* __restrict__ in,
                                                      unsigned short* __restrict__ out,
                                                      float* absOut, int n4) {
  int i0 = blockIdx.x * 256 + threadIdx.x;
  int stride = gridDim.x * 256;
  float s = 0.f;
  for (int i = i0; i < n4; i += stride) {
    float4 v = ((const float4*)in)[i];
    ushort4 o;
    o.x = f2h(v.x); o.y = f2h(v.y); o.z = f2h(v.z); o.w = f2h(v.w);
    ((ushort4*)out)[i] = o;
    s += fabsf(v.x) + fabsf(v.y) + fabsf(v.z) + fabsf(v.w);
  }
#pragma unroll
  for (int off = 32; off; off >>= 1) s += __shfl_xor(s, off);
  __shared__ float red[4];
  if ((threadIdx.x & 63) == 0) red[threadIdx.x >> 6] = s;
  __syncthreads();
  if (threadIdx.x == 0) atomicAdd(absOut, red[0] + red[1] + red[2] + red[3]);
}

// ---------------------------------------------------------------------------
// three weight matrices -> f16 in one launch (blockIdx.y selects matrix)
// ---------------------------------------------------------------------------
__global__ __launch_bounds__(256) void f2h3_kernel(const float* __restrict__ a,
                                                   const float* __restrict__ b,
                                                   const float* __restrict__ c,
                                                   unsigned short* __restrict__ oa,
                                                   unsigned short* __restrict__ ob,
                                                   unsigned short* __restrict__ oc,
                                                   int n4) {
  int i = blockIdx.x * 256 + threadIdx.x;
  if (i >= n4) return;
  const float* in = (blockIdx.y == 0) ? a : (blockIdx.y == 1) ? b : c;
  unsigned short* out = (blockIdx.y == 0) ? oa : (blockIdx.y == 1) ? ob : oc;
  float4 v = ((const float4*)in)[i];
  ushort4 o;
  o.x = f2h(v.x); o.y = f2h(v.y); o.z = f2h(v.z); o.w = f2h(v.w);
  ((ushort4*)out)[i] = o;
}

// ---------------------------------------------------------------------------
// 16-bit transpose per batch: in [R][C] -> out [C][R]
// ---------------------------------------------------------------------------
__global__ __launch_bounds__(256) void transpose_h16(const unsigned short* __restrict__ in,
                                                     unsigned short* __restrict__ out,
                                                     int R, int C) {
  __shared__ unsigned short t[32][33];
  const int z = blockIdx.z;
  in  += (long long)z * R * C;
  out += (long long)z * R * C;
  const int c0 = blockIdx.x * 32, r0 = blockIdx.y * 32;
#pragma unroll
  for (int i = 0; i < 4; ++i) {
    int r = threadIdx.y + i * 8;
    t[r][threadIdx.x] = in[(long long)(r0 + r) * C + c0 + threadIdx.x];
  }
  __syncthreads();
#pragma unroll
  for (int i = 0; i < 4; ++i) {
    int r = threadIdx.y + i * 8;
    out[(long long)(c0 + r) * R + r0 + threadIdx.x] = t[threadIdx.x][r];
  }
}

// ---------------------------------------------------------------------------
// f16 MFMA GEMM NT (m97 structure): C[m,n] = scale * sum_k A[m,k]*B[n,k]
// 128x128 tile, BK=32, 256 thr (4 waves), 4x4 16x16x32 MFMAs per wave.
// ---------------------------------------------------------------------------
template <bool OUT_F16>
__global__ __launch_bounds__(256) void gemm_nt_mfma(const unsigned short* __restrict__ A,
                                                    const unsigned short* __restrict__ B,
                                                    void* __restrict__ Cv,
                                                    int M, int N, int K,
                                                    long long sA, long long sB, long long sC,
                                                    float scale) {
  const int bz = blockIdx.z;
  A += (long long)bz * sA;
  B += (long long)bz * sB;

  __shared__ __align__(16) unsigned short As[128 * 32];   // linear, 64B row stride
  __shared__ __align__(16) unsigned short Bs[128 * 32];

  const int tid = threadIdx.x;
  const int lane = tid & 63;
  const int w = tid >> 6;
  const int wm = (w & 1) << 6;
  const int wn = (w >> 1) << 6;
  const int m0 = blockIdx.y * 128, n0 = blockIdx.x * 128;

  f32x4 acc[4][4] = {};

  const int srow = tid >> 2;
  const int scol = ((lane & 3) ^ ((lane >> 3) & 3)) * 8;
  unsigned short* aL0 = &As[(w * 16) * 32];
  unsigned short* aL1 = &As[(64 + w * 16) * 32];
  unsigned short* bL0 = &Bs[(w * 16) * 32];
  unsigned short* bL1 = &Bs[(64 + w * 16) * 32];

  const int fm = lane & 15;
  const int col8 = (((lane >> 4) ^ ((lane >> 1) & 3)) * 8);
  const unsigned short* afp[4];
  const unsigned short* bfp[4];
#pragma unroll
  for (int mi = 0; mi < 4; ++mi) {
    afp[mi] = &As[(wm + mi * 16 + fm) * 32 + col8];
    bfp[mi] = &Bs[(wn + mi * 16 + fm) * 32 + col8];
  }

  const unsigned short* gA0 = A + (long long)(m0 + srow) * K + scol;
  const unsigned short* gA1 = A + (long long)(m0 + 64 + srow) * K + scol;
  const unsigned short* gB0 = B + (long long)(n0 + srow) * K + scol;
  const unsigned short* gB1 = B + (long long)(n0 + 64 + srow) * K + scol;

  for (int k0 = 0; k0 < K; k0 += 32) {
    GLD16(gA0 + k0, aL0);
    GLD16(gA1 + k0, aL1);
    GLD16(gB0 + k0, bL0);
    GLD16(gB1 + k0, bL1);
    __syncthreads();

    f16x8 af[4], bfr[4];
#pragma unroll
    for (int mi = 0; mi < 4; ++mi) af[mi] = *(const f16x8*)afp[mi];
#pragma unroll
    for (int ni = 0; ni < 4; ++ni) bfr[ni] = *(const f16x8*)bfp[ni];
#pragma unroll
    for (int mi = 0; mi < 4; ++mi)
#pragma unroll
      for (int ni = 0; ni < 4; ++ni)
        acc[mi][ni] = __builtin_amdgcn_mfma_f32_16x16x32_f16(af[mi], bfr[ni],
                                                             acc[mi][ni], 0, 0, 0);
    __syncthreads();
  }

  const int cm = (lane >> 4) * 4;
  const int cn = lane & 15;
#pragma unroll
  for (int mi = 0; mi < 4; ++mi)
#pragma unroll
    for (int ni = 0; ni < 4; ++ni) {
#pragma unroll
      for (int r = 0; r < 4; ++r) {
        long long m = m0 + wm + mi * 16 + cm + r;
        long long n = n0 + wn + ni * 16 + cn;
        float v = acc[mi][ni][r] * scale;
        if (OUT_F16)
          ((unsigned short*)Cv)[(long long)bz * sC + m * N + n] = f2h(v);
        else
          ((float*)Cv)[(long long)bz * sC + m * N + n] = v;
      }
    }
}

// ---------------------------------------------------------------------------
// Wave-per-row sparsemax/softmax, element e = lane*32 + v.
// v3: original scores staged in LDS (chunk-XOR-swizzled, conflict-free both
// directions) so only the 32-reg sort array stays in VGPRs -> 4 waves/SIMD.
// Bitonic merges use the uniform-sign-flip trick: per kl iteration the merge
// direction dsc=((lane&kl)==0) is shared by all CE partners, so negate r on
// !dsc lanes once, run a COMPILE-TIME descending network (no cndmask), negate
// back (folded into a running sign mask). Cross-lane exchange uses immediate
// ds_swizzle (jl<=16, zero addr VALU) / hoisted ds_bpermute (jl=32).
// All transforms are bit-exact vs the previous version.
// ---------------------------------------------------------------------------
template <int K, int J>
__device__ __forceinline__ void intra_s(float (&r)[32]) {
#pragma unroll
  for (int v = 0; v < 32; ++v)
    if ((v & J) == 0) {
      const int u = v | J;
      const bool dsc = ((v & K) == 0);
      float a = r[v], b = r[u];
      float mx = fmaxf(a, b), mn = fminf(a, b);
      r[v] = dsc ? mx : mn;
      r[u] = dsc ? mn : mx;
    }
}

template <int J>
__device__ __forceinline__ void intra_desc(float (&r)[32]) {
#pragma unroll
  for (int v = 0; v < 32; ++v)
    if ((v & J) == 0) {
      const int u = v | J;
      float a = r[v], b = r[u];
      r[v] = fmaxf(a, b);
      r[u] = fminf(a, b);
    }
}

template <int JL>
__device__ __forceinline__ void cross_desc(float (&r)[32], int lane, int bp32) {
  const bool keepmax = ((lane & JL) == 0);
#pragma unroll
  for (int v = 0; v < 32; ++v) {
    int av = __builtin_bit_cast(int, r[v]);
    int bv;
    if constexpr (JL == 32)
      bv = __builtin_amdgcn_ds_bpermute(bp32, av);
    else
      bv = __builtin_amdgcn_ds_swizzle(av, (JL << 10) | 0x1F);  // xor-mode swizzle
    float b = __builtin_bit_cast(float, bv);
    float mx = fmaxf(r[v], b), mn = fminf(r[v], b);
    r[v] = keepmax ? mx : mn;
  }
}

__device__ __forceinline__ void signfix(float (&r)[32], unsigned fix) {
#pragma unroll
  for (int v = 0; v < 32; ++v)
    r[v] = __builtin_bit_cast(float, __builtin_bit_cast(unsigned, r[v]) ^ fix);
}

__global__ __launch_bounds__(256, 4) void attn_row_wave(const float* __restrict__ scores,
                                                        unsigned short* __restrict__ attn,
                                                        const float* __restrict__ absSum) {
  __shared__ float zs[4][2048];                  // 32 KB: raw scores, one row/wave
  const int tid = threadIdx.x;
  const int lane = tid & 63;
  const int wv = tid >> 6;
  const int row = blockIdx.x * 4 + wv;
  const float* rowp = scores + (long long)row * NROW;
  unsigned short* aout = attn + (long long)row * NROW;
  float* zrow = zs[wv];
  const int bp32 = (lane ^ 32) << 2;

  // Coalesced load (lane-contiguous float4) -> LDS with 16B-chunk XOR swizzle:
  // store chunk' = (chunk&~7) | ((chunk ^ (chunk>>3)) & 7). Read side (lane
  // reads its own 128B in sort order) hits 8 distinct bank groups per issue.
  float lm = -INFINITY;
#pragma unroll
  for (int q = 0; q < 8; ++q) {
    float4 v = ((const float4*)rowp)[q * 64 + lane];
    int chunk = q * 64 + lane;
    int swz = (chunk & ~7) | ((chunk ^ (chunk >> 3)) & 7);
    ((float4*)zrow)[swz] = v;
    lm = fmaxf(lm, fmaxf(fmaxf(v.x, v.y), fmaxf(v.z, v.w)));
  }
#pragma unroll
  for (int off = 32; off; off >>= 1) lm = fmaxf(lm, __shfl_xor(lm, off, 64));
  __syncthreads();

  const bool use_softmax = (absSum[0] * (1.0f / TOTX)) >= 1.0f;

  if (use_softmax) {
    float z[32];
    float ls = 0.f;
#pragma unroll
    for (int q = 0; q < 8; ++q) {
      int swz = lane * 8 + (q ^ (lane & 7));
      float4 v = ((const float4*)zrow)[swz];
      z[q * 4 + 0] = expf(v.x - lm); z[q * 4 + 1] = expf(v.y - lm);
      z[q * 4 + 2] = expf(v.z - lm); z[q * 4 + 3] = expf(v.w - lm);
      ls += z[q * 4 + 0] + z[q * 4 + 1] + z[q * 4 + 2] + z[q * 4 + 3];
    }
#pragma unroll
    for (int off = 32; off; off >>= 1) ls += __shfl_xor(ls, off, 64);
    float inv = 1.0f / ls;
    ushort4* op = (ushort4*)(aout + lane * 32);
#pragma unroll
    for (int q = 0; q < 8; ++q) {
      ushort4 o;
      o.x = f2h(z[q * 4 + 0] * inv); o.y = f2h(z[q * 4 + 1] * inv);
      o.z = f2h(z[q * 4 + 2] * inv); o.w = f2h(z[q * 4 + 3] * inv);
      op[q] = o;
    }
    return;
  }

  // ---- sparsemax ----
  float r[32];
  float lsum = 0.f;
#pragma unroll
  for (int q = 0; q < 8; ++q) {
    int swz = lane * 8 + (q ^ (lane & 7));
    float4 v = ((const float4*)zrow)[swz];
    r[q * 4 + 0] = v.x - lm; r[q * 4 + 1] = v.y - lm;
    r[q * 4 + 2] = v.z - lm; r[q * 4 + 3] = v.w - lm;
    lsum += r[q * 4 + 0] + r[q * 4 + 1] + r[q * 4 + 2] + r[q * 4 + 3];
  }
#pragma unroll
  for (int off = 32; off; off >>= 1) lsum += __shfl_xor(lsum, off, 64);
  const float step = (lsum - 1.0f) * (1.0f / (float)NROW);

  // per-lane bitonic presort (compile-time directions)
  intra_s<2, 1>(r);
  intra_s<4, 2>(r); intra_s<4, 1>(r);
  intra_s<8, 4>(r); intra_s<8, 2>(r); intra_s<8, 1>(r);
  intra_s<16, 8>(r); intra_s<16, 4>(r); intra_s<16, 2>(r); intra_s<16, 1>(r);

  // merge ladder with running sign mask (negate-on-!dsc => all merges desc)
  unsigned cur = (unsigned)(lane & 1) << 31;               // kl=1
  signfix(r, cur);
  intra_desc<16>(r); intra_desc<8>(r); intra_desc<4>(r);
  intra_desc<2>(r); intra_desc<1>(r);

  { unsigned want = (unsigned)(lane & 2) << 30;            // kl=2
    signfix(r, cur ^ want); cur = want; }
  cross_desc<1>(r, lane, bp32);
  intra_desc<16>(r); intra_desc<8>(r); intra_desc<4>(r);
  intra_desc<2>(r); intra_desc<1>(r);

  { unsigned want = (unsigned)(lane & 4) << 29;            // kl=4
    signfix(r, cur ^ want); cur = want; }
  cross_desc<2>(r, lane, bp32); cross_desc<1>(r, lane, bp32);
  intra_desc<16>(r); intra_desc<8>(r); intra_desc<4>(r);
  intra_desc<2>(r); intra_desc<1>(r);

  { unsigned want = (unsigned)(lane & 8) << 28;            // kl=8
    signfix(r, cur ^ want); cur = want; }
  cross_desc<4>(r, lane, bp32); cross_desc<2>(r, lane, bp32);
  cross_desc<1>(r, lane, bp32);
  intra_desc<16>(r); intra_desc<8>(r); intra_desc<4>(r);
  intra_desc<2>(r); intra_desc<1>(r);

  { unsigned want = (unsigned)(lane & 16) << 27;           // kl=16
    signfix(r, cur ^ want); cur = want; }
  cross_desc<8>(r, lane, bp32); cross_desc<4>(r, lane, bp32);
  cross_desc<2>(r, lane, bp32); cross_desc<1>(r, lane, bp32);
  intra_desc<16>(r); intra_desc<8>(r); intra_desc<4>(r);
  intra_desc<2>(r); intra_desc<1>(r);

  { unsigned want = (unsigned)(lane & 32) << 26;           // kl=32
    signfix(r, cur ^ want); cur = want; }
  cross_desc<16>(r, lane, bp32); cross_desc<8>(r, lane, bp32);
  cross_desc<4>(r, lane, bp32); cross_desc<2>(r, lane, bp32);
  cross_desc<1>(r, lane, bp32);
  intra_desc<16>(r); intra_desc<8>(r); intra_desc<4>(r);
  intra_desc<2>(r); intra_desc<1>(r);

  signfix(r, cur);                                         // kl=64: dsc==true everywhere
  cross_desc<32>(r, lane, bp32); cross_desc<16>(r, lane, bp32);
  cross_desc<8>(r, lane, bp32); cross_desc<4>(r, lane, bp32);
  cross_desc<2>(r, lane, bp32); cross_desc<1>(r, lane, bp32);
  intra_desc<16>(r); intra_desc<8>(r); intra_desc<4>(r);
  intra_desc<2>(r); intra_desc<1>(r);

  // k = count(sorted > step)
  float lcnt = 0.f;
#pragma unroll
  for (int v = 0; v < 32; ++v) lcnt += (r[v] > step) ? 1.0f : 0.0f;
#pragma unroll
  for (int off = 32; off; off >>= 1) lcnt += __shfl_xor(lcnt, off, 64);
  const float kf = lcnt;

  // inclusive cumsum over e: local sequential + wave scan of lane totals
  float run = 0.f;
#pragma unroll
  for (int v = 0; v < 32; ++v) { run += r[v]; r[v] = run; }
  float pre = run;
#pragma unroll
  for (int off = 1; off < 64; off <<= 1) {
    float t = __shfl_up(pre, off, 64);
    if (lane >= off) pre += t;
  }
  pre -= run;  // exclusive prefix of lane totals
#pragma unroll
  for (int v = 0; v < 32; ++v) r[v] += pre;

  const float inv_k = 1.0f / kf;
  const float c1 = 1.0f + step * kf;
  ushort4* op = (ushort4*)(aout + lane * 32);
#pragma unroll
  for (int q = 0; q < 8; ++q) {
    int swz = lane * 8 + (q ^ (lane & 7));
    float4 v = ((const float4*)zrow)[swz];
    ushort4 o;
    o.x = f2h(fmaxf((v.x - lm) - (r[q * 4 + 0] - c1) * inv_k, 0.0f));
    o.y = f2h(fmaxf((v.y - lm) - (r[q * 4 + 1] - c1) * inv_k, 0.0f));
    o.z = f2h(fmaxf((v.z - lm) - (r[q * 4 + 2] - c1) * inv_k, 0.0f));
    o.w = f2h(fmaxf((v.w - lm) - (r[q * 4 + 3] - c1) * inv_k, 0.0f));
    op[q] = o;
  }
}

// ---------------------------------------------------------------------------
extern "C" void kernel_launch(void* const* d_in, const int* in_sizes, int n_in,
                              void* d_out, int out_size, void* d_ws, size_t ws_size,
                              hipStream_t stream) {
  const float* x  = (const float*)d_in[0];
  const float* Wq = (const float*)d_in[1];
  const float* Wk = (const float*)d_in[2];
  const float* Wv = (const float*)d_in[3];
  float* out = (float*)d_out;

  const long long NX = (long long)B_ * S_ * D_;   // 8M
  const long long NW = (long long)H_ * D_;        // 1M

  // Workspace layout with aliasing (total 144 MB + 4 B):
  //  [0,64MB):    x16(16) Wq16(2) Wk16(2) Wv16(2) V16(16) slack -> later Sc (fp32, 64MB)
  //  [64,80MB):   Vt16 (16MB, persists to PV)
  //  [80,96MB):   Q16 (16MB)   [96,112MB): K16 (16MB)
  //  [112,144MB): A16 (f16 attention, 32MB)
  //  [144MB]:     flag
  char* base = (char*)d_ws;
  unsigned short* x16  = (unsigned short*)(base);
  unsigned short* Wq16 = (unsigned short*)(base + (16ll << 20));
  unsigned short* Wk16 = (unsigned short*)(base + (18ll << 20));
  unsigned short* Wv16 = (unsigned short*)(base + (20ll << 20));
  unsigned short* V16  = (unsigned short*)(base + (22ll << 20));
  float*          Sc   = (float*)(base);
  unsigned short* Vt16 = (unsigned short*)(base + (64ll << 20));
  unsigned short* Q16  = (unsigned short*)(base + (80ll << 20));
  unsigned short* K16  = (unsigned short*)(base + (96ll << 20));
  unsigned short* A16  = (unsigned short*)(base + (112ll << 20));
  float*          flag = (float*)(base + (144ll << 20));

  hipMemsetAsync(flag, 0, sizeof(float), stream);

  // fused x->f16 + abs-sum (grid-stride, 1024 blocks -> 1024 atomics)
  f2h_abs_kernel<<<1024, 256, 0, stream>>>(x, x16, flag, (int)(NX / 4));
  // W -> f16, one launch
  f2h3_kernel<<<dim3((int)(NW / 4 + 255) / 256, 3), 256, 0, stream>>>(
      Wq, Wk, Wv, Wq16, Wk16, Wv16, (int)(NW / 4));

  // Projections: Q/K/V = x @ W^T  (M=8192, N=1024, K=1024), f16 out
  {
    dim3 grid(H_ / 128, (B_ * S_) / 128, 1);
    gemm_nt_mfma<true><<<grid, 256, 0, stream>>>(x16, Wq16, Q16, B_ * S_, H_, D_, 0, 0, 0, 1.0f);
    gemm_nt_mfma<true><<<grid, 256, 0, stream>>>(x16, Wk16, K16, B_ * S_, H_, D_, 0, 0, 0, 1.0f);
    gemm_nt_mfma<true><<<grid, 256, 0, stream>>>(x16, Wv16, V16, B_ * S_, H_, D_, 0, 0, 0, 1.0f);
  }

  // V^T per batch: [S][H] -> [H][S]
  {
    dim3 grid(H_ / 32, S_ / 32, B_);
    transpose_h16<<<grid, dim3(32, 8), 0, stream>>>(V16, Vt16, S_, H_);
  }

  // scores = Q @ K^T / 32 (batched, fp32 out; overwrites x16/W/V16 — all dead)
  {
    dim3 grid(S_ / 128, S_ / 128, B_);
    gemm_nt_mfma<false><<<grid, 256, 0, stream>>>(Q16, K16, Sc, S_, S_, H_,
                                                  (long long)S_ * H_, (long long)S_ * H_,
                                                  (long long)S_ * S_, 1.0f / 32.0f);
  }

  // attention = sparsemax-or-softmax(scores) -> f16 (one wave per row)
  attn_row_wave<<<(B_ * S_) / 4, 256, 0, stream>>>(Sc, A16, flag);

  // out = attention @ Vt^T, f16 MFMA, fp32 out
  {
    dim3 grid(H_ / 128, S_ / 128, B_);
    gemm_nt_mfma<false><<<grid, 256, 0, stream>>>(A16, Vt16, out, S_, H_, S_,
                                                  (long long)S_ * S_, (long long)H_ * S_,
                                                  (long long)S_ * H_, 1.0f);
  }
}

// Round 2
// 378.603 us; speedup vs baseline: 1.1618x; 1.0959x over previous
//
#include <hip/hip_runtime.h>
#include <math.h>

// Problem constants
#define B_   4
#define S_   2048
#define D_   1024
#define H_   1024
#define NROW 2048
#define TOTX 8388608.0f            // B_*S_*D_ elements of x

typedef _Float16 f16x8 __attribute__((ext_vector_type(8)));
typedef float f32x4 __attribute__((ext_vector_type(4)));

__device__ __forceinline__ unsigned short f2h(float f) {
  _Float16 h = (_Float16)f;                       // v_cvt_f16_f32, RNE
  return __builtin_bit_cast(unsigned short, h);
}

// async global->LDS, 16B per lane, lands at ldsbase + lane*16
#define GLD16(gp, lp)                                                            \
  __builtin_amdgcn_global_load_lds(                                              \
      (__attribute__((address_space(1))) void*)(gp),                             \
      (__attribute__((address_space(3))) void*)(lp), 16, 0, 0)

// ---------------------------------------------------------------------------
// fused float->f16 conversion + abs-sum for x (one pass over 32 MB)
// ---------------------------------------------------------------------------
__global__ __launch_bounds__(256) void f2h_abs_kernel(const float* __restrict__ in,
                                                      unsigned short* __restrict__ out,
                                                      float* absOut, int n4) {
  int i0 = blockIdx.x * 256 + threadIdx.x;
  int stride = gridDim.x * 256;
  float s = 0.f;
  for (int i = i0; i < n4; i += stride) {
    float4 v = ((const float4*)in)[i];
    ushort4 o;
    o.x = f2h(v.x); o.y = f2h(v.y); o.z = f2h(v.z); o.w = f2h(v.w);
    ((ushort4*)out)[i] = o;
    s += fabsf(v.x) + fabsf(v.y) + fabsf(v.z) + fabsf(v.w);
  }
#pragma unroll
  for (int off = 32; off; off >>= 1) s += __shfl_xor(s, off);
  __shared__ float red[4];
  if ((threadIdx.x & 63) == 0) red[threadIdx.x >> 6] = s;
  __syncthreads();
  if (threadIdx.x == 0) atomicAdd(absOut, red[0] + red[1] + red[2] + red[3]);
}

// ---------------------------------------------------------------------------
// three weight matrices -> f16 in one launch (blockIdx.y selects matrix)
// ---------------------------------------------------------------------------
__global__ __launch_bounds__(256) void f2h3_kernel(const float* __restrict__ a,
                                                   const float* __restrict__ b,
                                                   const float* __restrict__ c,
                                                   unsigned short* __restrict__ oa,
                                                   unsigned short* __restrict__ ob,
                                                   unsigned short* __restrict__ oc,
                                                   int n4) {
  int i = blockIdx.x * 256 + threadIdx.x;
  if (i >= n4) return;
  const float* in = (blockIdx.y == 0) ? a : (blockIdx.y == 1) ? b : c;
  unsigned short* out = (blockIdx.y == 0) ? oa : (blockIdx.y == 1) ? ob : oc;
  float4 v = ((const float4*)in)[i];
  ushort4 o;
  o.x = f2h(v.x); o.y = f2h(v.y); o.z = f2h(v.z); o.w = f2h(v.w);
  ((ushort4*)out)[i] = o;
}

// ---------------------------------------------------------------------------
// 16-bit transpose per batch: in [R][C] -> out [C][R]
// ---------------------------------------------------------------------------
__global__ __launch_bounds__(256) void transpose_h16(const unsigned short* __restrict__ in,
                                                     unsigned short* __restrict__ out,
                                                     int R, int C) {
  __shared__ unsigned short t[32][33];
  const int z = blockIdx.z;
  in  += (long long)z * R * C;
  out += (long long)z * R * C;
  const int c0 = blockIdx.x * 32, r0 = blockIdx.y * 32;
#pragma unroll
  for (int i = 0; i < 4; ++i) {
    int r = threadIdx.y + i * 8;
    t[r][threadIdx.x] = in[(long long)(r0 + r) * C + c0 + threadIdx.x];
  }
  __syncthreads();
#pragma unroll
  for (int i = 0; i < 4; ++i) {
    int r = threadIdx.y + i * 8;
    out[(long long)(c0 + r) * R + r0 + threadIdx.x] = t[threadIdx.x][r];
  }
}

// ---------------------------------------------------------------------------
// f16 MFMA GEMM NT, 8-wave 256x256 tile, BK=32, phase-interleaved schedule
// (T2 swizzle + T3/T4 counted staging + T5 setprio, per the 256^2 template).
// C[m,n] = scale * sum_k A[m,k]*B[n,k].
// 512 thr = 8 waves (2 row-bands x 4 col-bands); wave tile 128x64 (8x4 frags).
// LDS: 2 x (A 256x32 | B 256x32) f16 = 64 KiB, double buffered.
// Per K-tile: phase A {stage all 4 rounds of t+1; ds_read A(mi0-3)+B; bar;
// lgkm; 16 MFMA} phase B {ds_read A(mi4-7); bar; lgkm; 16 MFMA; vmcnt(0); bar}.
// Stage/read swizzle pair is identical to the previously-verified 128^2 kernel.
// ---------------------------------------------------------------------------
template <bool OUT_F16>
__global__ __launch_bounds__(512, 2) void gemm8_nt(const unsigned short* __restrict__ A,
                                                   const unsigned short* __restrict__ B,
                                                   void* __restrict__ Cv,
                                                   int M, int N, int K,
                                                   long long sA, long long sB, long long sC,
                                                   float scale) {
  const int bz = blockIdx.z;
  A += (long long)bz * sA;
  B += (long long)bz * sB;

  __shared__ __align__(16) unsigned short lds[2][2][8192];  // [buf][A|B][256*32]

  const int tid = threadIdx.x;
  const int lane = tid & 63;
  const int w = tid >> 6;
  const int wr = w >> 2;          // 0..1 : 128-row band
  const int wc = w & 3;           // 0..3 : 64-col band
  const int m0 = blockIdx.y * 256, n0 = blockIdx.x * 256;

  f32x4 acc[8][4] = {};

  // staging: wave w, lane l -> row w*16 + (l>>2), col chunk (l&3)^((l>>3)&3)
  const int srow = w * 16 + (lane >> 2);                  // 0..127
  const int scol = ((lane & 3) ^ ((lane >> 3) & 3)) * 8;  // f16 col
  const unsigned short* gA0 = A + (long long)(m0 + srow) * K + scol;
  const unsigned short* gA1 = gA0 + (long long)128 * K;
  const unsigned short* gB0 = B + (long long)(n0 + srow) * K + scol;
  const unsigned short* gB1 = gB0 + (long long)128 * K;
  const int wb = w * 512;         // u16 offset of wave's 1KB staging slot

  // fragment read offsets (u16 units), same swizzle family as staging
  const int fm = lane & 15;
  const int col8 = ((lane >> 4) ^ ((lane >> 1) & 3)) * 8;
  int aoff[8], boff[4];
#pragma unroll
  for (int mi = 0; mi < 8; ++mi) aoff[mi] = (wr * 128 + mi * 16 + fm) * 32 + col8;
#pragma unroll
  for (int ni = 0; ni < 4; ++ni) boff[ni] = (wc * 64 + ni * 16 + fm) * 32 + col8;

  const int nt = K >> 5;

#define STAGE8(nb, k0)                                   \
  do {                                                   \
    GLD16(gA0 + (k0), &lds[nb][0][wb]);                  \
    GLD16(gA1 + (k0), &lds[nb][0][4096 + wb]);           \
    GLD16(gB0 + (k0), &lds[nb][1][wb]);                  \
    GLD16(gB1 + (k0), &lds[nb][1][4096 + wb]);           \
  } while (0)

  // prologue: tile 0 -> buf 0
  STAGE8(0, 0);
  asm volatile("s_waitcnt vmcnt(0)" ::: "memory");
  __builtin_amdgcn_s_barrier();

  for (int t = 0; t < nt; ++t) {
    const int cur = t & 1;
    const unsigned short* Ar = lds[cur][0];
    const unsigned short* Br = lds[cur][1];
    // ---- phase A: front-load all 4 stage rounds for t+1, read A0-3 + B ----
    if (t + 1 < nt) {
      const int k1 = (t + 1) << 5;
      if (cur) STAGE8(0, k1); else STAGE8(1, k1);
    }
    f16x8 af[4], bf[4];
#pragma unroll
    for (int mi = 0; mi < 4; ++mi) af[mi] = *(const f16x8*)(Ar + aoff[mi]);
#pragma unroll
    for (int ni = 0; ni < 4; ++ni) bf[ni] = *(const f16x8*)(Br + boff[ni]);
    __builtin_amdgcn_s_barrier();
    asm volatile("s_waitcnt lgkmcnt(0)" ::: "memory");
    __builtin_amdgcn_sched_barrier(0);
    __builtin_amdgcn_s_setprio(1);
#pragma unroll
    for (int mi = 0; mi < 4; ++mi)
#pragma unroll
      for (int ni = 0; ni < 4; ++ni)
        acc[mi][ni] = __builtin_amdgcn_mfma_f32_16x16x32_f16(af[mi], bf[ni],
                                                             acc[mi][ni], 0, 0, 0);
    __builtin_amdgcn_s_setprio(0);
    __builtin_amdgcn_s_barrier();
    // ---- phase B: read A4-7, compute, then drain t+1's staging ----
    f16x8 ag[4];
#pragma unroll
    for (int mi = 0; mi < 4; ++mi) ag[mi] = *(const f16x8*)(Ar + aoff[mi + 4]);
    __builtin_amdgcn_s_barrier();
    asm volatile("s_waitcnt lgkmcnt(0)" ::: "memory");
    __builtin_amdgcn_sched_barrier(0);
    __builtin_amdgcn_s_setprio(1);
#pragma unroll
    for (int mi = 0; mi < 4; ++mi)
#pragma unroll
      for (int ni = 0; ni < 4; ++ni)
        acc[mi + 4][ni] = __builtin_amdgcn_mfma_f32_16x16x32_f16(ag[mi], bf[ni],
                                                                 acc[mi + 4][ni], 0, 0, 0);
    __builtin_amdgcn_s_setprio(0);
    if (t + 1 < nt) asm volatile("s_waitcnt vmcnt(0)" ::: "memory");
    __builtin_amdgcn_s_barrier();
  }
#undef STAGE8

  // epilogue: C/D layout col=lane&15, row=(lane>>4)*4+reg
  const int cm = (lane >> 4) * 4;
  const int cn = lane & 15;
#pragma unroll
  for (int mi = 0; mi < 8; ++mi)
#pragma unroll
    for (int ni = 0; ni < 4; ++ni) {
#pragma unroll
      for (int r = 0; r < 4; ++r) {
        long long m = m0 + wr * 128 + mi * 16 + cm + r;
        long long n = n0 + wc * 64 + ni * 16 + cn;
        float v = acc[mi][ni][r] * scale;
        if (OUT_F16)
          ((unsigned short*)Cv)[(long long)bz * sC + m * N + n] = f2h(v);
        else
          ((float*)Cv)[(long long)bz * sC + m * N + n] = v;
      }
    }
}

// ---------------------------------------------------------------------------
// Wave-per-row sparsemax/softmax, element e = lane*32 + v.
// v4: cross_desc restructured into {32 batched swizzles -> 32 CEs} with an
// explicit b[32] temp so the compiler can issue all swizzles back-to-back and
// use counted lgkmcnt waits instead of serial issue-wait-use chunks (round-1
// showed VGPR=44: allocator had no temps to batch with). Bit-exact.
// ---------------------------------------------------------------------------
template <int K, int J>
__device__ __forceinline__ void intra_s(float (&r)[32]) {
#pragma unroll
  for (int v = 0; v < 32; ++v)
    if ((v & J) == 0) {
      const int u = v | J;
      const bool dsc = ((v & K) == 0);
      float a = r[v], b = r[u];
      float mx = fmaxf(a, b), mn = fminf(a, b);
      r[v] = dsc ? mx : mn;
      r[u] = dsc ? mn : mx;
    }
}

template <int J>
__device__ __forceinline__ void intra_desc(float (&r)[32]) {
#pragma unroll
  for (int v = 0; v < 32; ++v)
    if ((v & J) == 0) {
      const int u = v | J;
      float a = r[v], b = r[u];
      r[v] = fmaxf(a, b);
      r[u] = fminf(a, b);
    }
}

template <int JL>
__device__ __forceinline__ void cross_desc(float (&r)[32], int lane, int bp32) {
  const bool keepmax = ((lane & JL) == 0);
  float b[32];
#pragma unroll
  for (int v = 0; v < 32; ++v) {
    int av = __builtin_bit_cast(int, r[v]);
    int bv;
    if constexpr (JL == 32)
      bv = __builtin_amdgcn_ds_bpermute(bp32, av);
    else
      bv = __builtin_amdgcn_ds_swizzle(av, (JL << 10) | 0x1F);  // xor-mode swizzle
    b[v] = __builtin_bit_cast(float, bv);
  }
#pragma unroll
  for (int v = 0; v < 32; ++v) {
    float mx = fmaxf(r[v], b[v]), mn = fminf(r[v], b[v]);
    r[v] = keepmax ? mx : mn;
  }
}

__device__ __forceinline__ void signfix(float (&r)[32], unsigned fix) {
#pragma unroll
  for (int v = 0; v < 32; ++v)
    r[v] = __builtin_bit_cast(float, __builtin_bit_cast(unsigned, r[v]) ^ fix);
}

__global__ __launch_bounds__(256, 4) void attn_row_wave(const float* __restrict__ scores,
                                                        unsigned short* __restrict__ attn,
                                                        const float* __restrict__ absSum) {
  __shared__ float zs[4][2048];                  // 32 KB: raw scores, one row/wave
  const int tid = threadIdx.x;
  const int lane = tid & 63;
  const int wv = tid >> 6;
  const int row = blockIdx.x * 4 + wv;
  const float* rowp = scores + (long long)row * NROW;
  unsigned short* aout = attn + (long long)row * NROW;
  float* zrow = zs[wv];
  const int bp32 = (lane ^ 32) << 2;

  // Coalesced load -> LDS with 16B-chunk XOR swizzle (conflict-free both ways)
  float lm = -INFINITY;
#pragma unroll
  for (int q = 0; q < 8; ++q) {
    float4 v = ((const float4*)rowp)[q * 64 + lane];
    int chunk = q * 64 + lane;
    int swz = (chunk & ~7) | ((chunk ^ (chunk >> 3)) & 7);
    ((float4*)zrow)[swz] = v;
    lm = fmaxf(lm, fmaxf(fmaxf(v.x, v.y), fmaxf(v.z, v.w)));
  }
#pragma unroll
  for (int off = 32; off; off >>= 1) lm = fmaxf(lm, __shfl_xor(lm, off, 64));
  __syncthreads();

  const bool use_softmax = (absSum[0] * (1.0f / TOTX)) >= 1.0f;

  if (use_softmax) {
    float z[32];
    float ls = 0.f;
#pragma unroll
    for (int q = 0; q < 8; ++q) {
      int swz = lane * 8 + (q ^ (lane & 7));
      float4 v = ((const float4*)zrow)[swz];
      z[q * 4 + 0] = expf(v.x - lm); z[q * 4 + 1] = expf(v.y - lm);
      z[q * 4 + 2] = expf(v.z - lm); z[q * 4 + 3] = expf(v.w - lm);
      ls += z[q * 4 + 0] + z[q * 4 + 1] + z[q * 4 + 2] + z[q * 4 + 3];
    }
#pragma unroll
    for (int off = 32; off; off >>= 1) ls += __shfl_xor(ls, off, 64);
    float inv = 1.0f / ls;
    ushort4* op = (ushort4*)(aout + lane * 32);
#pragma unroll
    for (int q = 0; q < 8; ++q) {
      ushort4 o;
      o.x = f2h(z[q * 4 + 0] * inv); o.y = f2h(z[q * 4 + 1] * inv);
      o.z = f2h(z[q * 4 + 2] * inv); o.w = f2h(z[q * 4 + 3] * inv);
      op[q] = o;
    }
    return;
  }

  // ---- sparsemax ----
  float r[32];
  float lsum = 0.f;
#pragma unroll
  for (int q = 0; q < 8; ++q) {
    int swz = lane * 8 + (q ^ (lane & 7));
    float4 v = ((const float4*)zrow)[swz];
    r[q * 4 + 0] = v.x - lm; r[q * 4 + 1] = v.y - lm;
    r[q * 4 + 2] = v.z - lm; r[q * 4 + 3] = v.w - lm;
    lsum += r[q * 4 + 0] + r[q * 4 + 1] + r[q * 4 + 2] + r[q * 4 + 3];
  }
#pragma unroll
  for (int off = 32; off; off >>= 1) lsum += __shfl_xor(lsum, off, 64);
  const float step = (lsum - 1.0f) * (1.0f / (float)NROW);

  // per-lane bitonic presort (compile-time directions)
  intra_s<2, 1>(r);
  intra_s<4, 2>(r); intra_s<4, 1>(r);
  intra_s<8, 4>(r); intra_s<8, 2>(r); intra_s<8, 1>(r);
  intra_s<16, 8>(r); intra_s<16, 4>(r); intra_s<16, 2>(r); intra_s<16, 1>(r);

  // merge ladder with running sign mask (negate-on-!dsc => all merges desc)
  unsigned cur = (unsigned)(lane & 1) << 31;               // kl=1
  signfix(r, cur);
  intra_desc<16>(r); intra_desc<8>(r); intra_desc<4>(r);
  intra_desc<2>(r); intra_desc<1>(r);

  { unsigned want = (unsigned)(lane & 2) << 30;            // kl=2
    signfix(r, cur ^ want); cur = want; }
  cross_desc<1>(r, lane, bp32);
  intra_desc<16>(r); intra_desc<8>(r); intra_desc<4>(r);
  intra_desc<2>(r); intra_desc<1>(r);

  { unsigned want = (unsigned)(lane & 4) << 29;            // kl=4
    signfix(r, cur ^ want); cur = want; }
  cross_desc<2>(r, lane, bp32); cross_desc<1>(r, lane, bp32);
  intra_desc<16>(r); intra_desc<8>(r); intra_desc<4>(r);
  intra_desc<2>(r); intra_desc<1>(r);

  { unsigned want = (unsigned)(lane & 8) << 28;            // kl=8
    signfix(r, cur ^ want); cur = want; }
  cross_desc<4>(r, lane, bp32); cross_desc<2>(r, lane, bp32);
  cross_desc<1>(r, lane, bp32);
  intra_desc<16>(r); intra_desc<8>(r); intra_desc<4>(r);
  intra_desc<2>(r); intra_desc<1>(r);

  { unsigned want = (unsigned)(lane & 16) << 27;           // kl=16
    signfix(r, cur ^ want); cur = want; }
  cross_desc<8>(r, lane, bp32); cross_desc<4>(r, lane, bp32);
  cross_desc<2>(r, lane, bp32); cross_desc<1>(r, lane, bp32);
  intra_desc<16>(r); intra_desc<8>(r); intra_desc<4>(r);
  intra_desc<2>(r); intra_desc<1>(r);

  { unsigned want = (unsigned)(lane & 32) << 26;           // kl=32
    signfix(r, cur ^ want); cur = want; }
  cross_desc<16>(r, lane, bp32); cross_desc<8>(r, lane, bp32);
  cross_desc<4>(r, lane, bp32); cross_desc<2>(r, lane, bp32);
  cross_desc<1>(r, lane, bp32);
  intra_desc<16>(r); intra_desc<8>(r); intra_desc<4>(r);
  intra_desc<2>(r); intra_desc<1>(r);

  signfix(r, cur);                                         // kl=64: dsc==true everywhere
  cross_desc<32>(r, lane, bp32); cross_desc<16>(r, lane, bp32);
  cross_desc<8>(r, lane, bp32); cross_desc<4>(r, lane, bp32);
  cross_desc<2>(r, lane, bp32); cross_desc<1>(r, lane, bp32);
  intra_desc<16>(r); intra_desc<8>(r); intra_desc<4>(r);
  intra_desc<2>(r); intra_desc<1>(r);

  // k = count(sorted > step)
  float lcnt = 0.f;
#pragma unroll
  for (int v = 0; v < 32; ++v) lcnt += (r[v] > step) ? 1.0f : 0.0f;
#pragma unroll
  for (int off = 32; off; off >>= 1) lcnt += __shfl_xor(lcnt, off, 64);
  const float kf = lcnt;

  // inclusive cumsum over e: local sequential + wave scan of lane totals
  float run = 0.f;
#pragma unroll
  for (int v = 0; v < 32; ++v) { run += r[v]; r[v] = run; }
  float pre = run;
#pragma unroll
  for (int off = 1; off < 64; off <<= 1) {
    float t = __shfl_up(pre, off, 64);
    if (lane >= off) pre += t;
  }
  pre -= run;  // exclusive prefix of lane totals
#pragma unroll
  for (int v = 0; v < 32; ++v) r[v] += pre;

  const float inv_k = 1.0f / kf;
  const float c1 = 1.0f + step * kf;
  ushort4* op = (ushort4*)(aout + lane * 32);
#pragma unroll
  for (int q = 0; q < 8; ++q) {
    int swz = lane * 8 + (q ^ (lane & 7));
    float4 v = ((const float4*)zrow)[swz];
    ushort4 o;
    o.x = f2h(fmaxf((v.x - lm) - (r[q * 4 + 0] - c1) * inv_k, 0.0f));
    o.y = f2h(fmaxf((v.y - lm) - (r[q * 4 + 1] - c1) * inv_k, 0.0f));
    o.z = f2h(fmaxf((v.z - lm) - (r[q * 4 + 2] - c1) * inv_k, 0.0f));
    o.w = f2h(fmaxf((v.w - lm) - (r[q * 4 + 3] - c1) * inv_k, 0.0f));
    op[q] = o;
  }
}

// ---------------------------------------------------------------------------
extern "C" void kernel_launch(void* const* d_in, const int* in_sizes, int n_in,
                              void* d_out, int out_size, void* d_ws, size_t ws_size,
                              hipStream_t stream) {
  const float* x  = (const float*)d_in[0];
  const float* Wq = (const float*)d_in[1];
  const float* Wk = (const float*)d_in[2];
  const float* Wv = (const float*)d_in[3];
  float* out = (float*)d_out;

  const long long NX = (long long)B_ * S_ * D_;   // 8M
  const long long NW = (long long)H_ * D_;        // 1M

  // Workspace layout (total 144 MB + 4 B):
  //  [0,16MB):    x16          -> later Sc (fp32, 64MB, overwrites x16+W)
  //  [16,22MB):   Wq16 Wk16 Wv16 (contiguous, 2MB apart -> fused proj)
  //  [64,80MB):   Vt16 (persists to PV)
  //  [80,96MB):   Q16   [96,112MB): K16   [112,128MB): V16
  //               (contiguous 16MB apart -> fused proj output, sC = 8M elems)
  //  [80,112MB):  A16 (f16 attention, 32MB; overwrites Q16/K16 after scores)
  //  [144MB]:     flag
  char* base = (char*)d_ws;
  unsigned short* x16  = (unsigned short*)(base);
  unsigned short* Wq16 = (unsigned short*)(base + (16ll << 20));
  unsigned short* Wk16 = (unsigned short*)(base + (18ll << 20));
  unsigned short* Wv16 = (unsigned short*)(base + (20ll << 20));
  float*          Sc   = (float*)(base);
  unsigned short* Vt16 = (unsigned short*)(base + (64ll << 20));
  unsigned short* Q16  = (unsigned short*)(base + (80ll << 20));
  unsigned short* K16  = (unsigned short*)(base + (96ll << 20));
  unsigned short* V16  = (unsigned short*)(base + (112ll << 20));
  unsigned short* A16  = (unsigned short*)(base + (80ll << 20));
  float*          flag = (float*)(base + (144ll << 20));

  hipMemsetAsync(flag, 0, sizeof(float), stream);

  // fused x->f16 + abs-sum (grid-stride)
  f2h_abs_kernel<<<1024, 256, 0, stream>>>(x, x16, flag, (int)(NX / 4));
  // W -> f16, one launch
  f2h3_kernel<<<dim3((int)(NW / 4 + 255) / 256, 3), 256, 0, stream>>>(
      Wq, Wk, Wv, Wq16, Wk16, Wv16, (int)(NW / 4));

  // Projections fused: z selects W (stride 1M elems) and output (stride 8M elems)
  {
    dim3 grid(H_ / 256, (B_ * S_) / 256, 3);   // 4 x 32 x 3 = 384 blocks
    gemm8_nt<true><<<grid, 512, 0, stream>>>(x16, Wq16, Q16, B_ * S_, H_, D_,
                                             0, (long long)NW, (long long)(8ll << 20),
                                             1.0f);
  }

  // V^T per batch: [S][H] -> [H][S]
  {
    dim3 grid(H_ / 32, S_ / 32, B_);
    transpose_h16<<<grid, dim3(32, 8), 0, stream>>>(V16, Vt16, S_, H_);
  }

  // scores = Q @ K^T / 32 (batched, fp32 out; overwrites x16/W — all dead)
  {
    dim3 grid(S_ / 256, S_ / 256, B_);         // 8 x 8 x 4 = 256 blocks
    gemm8_nt<false><<<grid, 512, 0, stream>>>(Q16, K16, Sc, S_, S_, H_,
                                              (long long)S_ * H_, (long long)S_ * H_,
                                              (long long)S_ * S_, 1.0f / 32.0f);
  }

  // attention = sparsemax-or-softmax(scores) -> f16 (one wave per row)
  attn_row_wave<<<(B_ * S_) / 4, 256, 0, stream>>>(Sc, A16, flag);

  // out = attention @ Vt^T, f16 MFMA, fp32 out
  {
    dim3 grid(H_ / 256, S_ / 256, B_);         // 4 x 8 x 4 = 128 blocks
    gemm8_nt<false><<<grid, 512, 0, stream>>>(A16, Vt16, out, S_, H_, S_,
                                              (long long)S_ * S_, (long long)H_ * S_,
                                              (long long)S_ * H_, 1.0f);
  }
}

// Round 3
// 337.997 us; speedup vs baseline: 1.3014x; 1.1201x over previous
//
#include <hip/hip_runtime.h>
#include <math.h>

// Problem constants
#define B_   4
#define S_   2048
#define D_   1024
#define H_   1024
#define NROW 2048
#define TOTX 8388608.0f            // B_*S_*D_ elements of x

typedef _Float16 f16x8 __attribute__((ext_vector_type(8)));
typedef float f32x4 __attribute__((ext_vector_type(4)));

__device__ __forceinline__ unsigned short f2h(float f) {
  _Float16 h = (_Float16)f;                       // v_cvt_f16_f32, RNE
  return __builtin_bit_cast(unsigned short, h);
}

// async global->LDS, 16B per lane, lands at ldsbase + lane*16
#define GLD16(gp, lp)                                                            \
  __builtin_amdgcn_global_load_lds(                                              \
      (__attribute__((address_space(1))) void*)(gp),                             \
      (__attribute__((address_space(3))) void*)(lp), 16, 0, 0)

// ---------------------------------------------------------------------------
// fused float->f16 conversion + abs-sum for x (one pass over 32 MB)
// ---------------------------------------------------------------------------
__global__ __launch_bounds__(256) void f2h_abs_kernel(const float* __restrict__ in,
                                                      unsigned short* __restrict__ out,
                                                      float* absOut, int n4) {
  int i0 = blockIdx.x * 256 + threadIdx.x;
  int stride = gridDim.x * 256;
  float s = 0.f;
  for (int i = i0; i < n4; i += stride) {
    float4 v = ((const float4*)in)[i];
    ushort4 o;
    o.x = f2h(v.x); o.y = f2h(v.y); o.z = f2h(v.z); o.w = f2h(v.w);
    ((ushort4*)out)[i] = o;
    s += fabsf(v.x) + fabsf(v.y) + fabsf(v.z) + fabsf(v.w);
  }
#pragma unroll
  for (int off = 32; off; off >>= 1) s += __shfl_xor(s, off);
  __shared__ float red[4];
  if ((threadIdx.x & 63) == 0) red[threadIdx.x >> 6] = s;
  __syncthreads();
  if (threadIdx.x == 0) atomicAdd(absOut, red[0] + red[1] + red[2] + red[3]);
}

// ---------------------------------------------------------------------------
// three weight matrices -> f16 in one launch (blockIdx.y selects matrix)
// ---------------------------------------------------------------------------
__global__ __launch_bounds__(256) void f2h3_kernel(const float* __restrict__ a,
                                                   const float* __restrict__ b,
                                                   const float* __restrict__ c,
                                                   unsigned short* __restrict__ oa,
                                                   unsigned short* __restrict__ ob,
                                                   unsigned short* __restrict__ oc,
                                                   int n4) {
  int i = blockIdx.x * 256 + threadIdx.x;
  if (i >= n4) return;
  const float* in = (blockIdx.y == 0) ? a : (blockIdx.y == 1) ? b : c;
  unsigned short* out = (blockIdx.y == 0) ? oa : (blockIdx.y == 1) ? ob : oc;
  float4 v = ((const float4*)in)[i];
  ushort4 o;
  o.x = f2h(v.x); o.y = f2h(v.y); o.z = f2h(v.z); o.w = f2h(v.w);
  ((ushort4*)out)[i] = o;
}

// ---------------------------------------------------------------------------
// 16-bit transpose per batch: in [R][C] -> out [C][R]
// ---------------------------------------------------------------------------
__global__ __launch_bounds__(256) void transpose_h16(const unsigned short* __restrict__ in,
                                                     unsigned short* __restrict__ out,
                                                     int R, int C) {
  __shared__ unsigned short t[32][33];
  const int z = blockIdx.z;
  in  += (long long)z * R * C;
  out += (long long)z * R * C;
  const int c0 = blockIdx.x * 32, r0 = blockIdx.y * 32;
#pragma unroll
  for (int i = 0; i < 4; ++i) {
    int r = threadIdx.y + i * 8;
    t[r][threadIdx.x] = in[(long long)(r0 + r) * C + c0 + threadIdx.x];
  }
  __syncthreads();
#pragma unroll
  for (int i = 0; i < 4; ++i) {
    int r = threadIdx.y + i * 8;
    out[(long long)(c0 + r) * R + r0 + threadIdx.x] = t[threadIdx.x][r];
  }
}

// ---------------------------------------------------------------------------
// f16 MFMA GEMM NT, 8 waves, BN=256, BM = MI*32 (MI=8 -> 256x256, MI=4 ->
// 128x256). BK=32, double-buffered LDS with COUNTED vmcnt (T4): tile t+2 is
// staged into the buffer t just vacated (after a read-done barrier), and the
// end-of-iter wait is vmcnt(NLD) -- never 0 in the main loop, so NLD loads
// stay in flight across every barrier. 2 barriers per K-tile.
// C[m,n] = scale * sum_k A[m,k]*B[n,k].
// ---------------------------------------------------------------------------
template <int MI, bool OUT_F16>
__global__ __launch_bounds__(512, 2) void gemm8_nt(const unsigned short* __restrict__ A,
                                                   const unsigned short* __restrict__ B,
                                                   void* __restrict__ Cv,
                                                   int M, int N, int K,
                                                   long long sA, long long sB, long long sC,
                                                   float scale) {
  constexpr int BM  = MI * 32;          // 256 or 128
  constexpr int ASZ = BM * 32;          // u16 per A tile
  constexpr int BSZ = 256 * 32;         // u16 per B tile
  constexpr int TSZ = ASZ + BSZ;        // u16 per buffer
  constexpr int MH  = MI / 2;           // frags per phase-half

  const int bz = blockIdx.z;
  A += (long long)bz * sA;
  B += (long long)bz * sB;

  __shared__ __align__(16) unsigned short lds[2 * TSZ];

  const int tid = threadIdx.x;
  const int lane = tid & 63;
  const int w = tid >> 6;
  const int wr = w >> 2;          // 0..1 : row band (BM/2 rows)
  const int wc = w & 3;           // 0..3 : 64-col band
  const int m0 = blockIdx.y * BM, n0 = blockIdx.x * 256;

  f32x4 acc[MI][4] = {};

  // staging: 512 threads, lane l of wave w -> row tid>>2 (0..127), chunk swizzle
  const int srow = tid >> 2;
  const int scol = ((lane & 3) ^ ((lane >> 3) & 3)) * 8;
  const unsigned short* gA0 = A + (long long)(m0 + srow) * K + scol;
  const unsigned short* gA1 = gA0 + (long long)128 * K;   // MI==8 only
  const unsigned short* gB0 = B + (long long)(n0 + srow) * K + scol;
  const unsigned short* gB1 = gB0 + (long long)128 * K;
  const int wb = w * 512;

  // fragment read offsets (u16 units), same swizzle family as staging
  const int fm = lane & 15;
  const int col8 = ((lane >> 4) ^ ((lane >> 1) & 3)) * 8;
  int aoff[MI], boff[4];
#pragma unroll
  for (int mi = 0; mi < MI; ++mi) aoff[mi] = (wr * (MI * 16) + mi * 16 + fm) * 32 + col8;
#pragma unroll
  for (int ni = 0; ni < 4; ++ni) boff[ni] = ASZ + (wc * 64 + ni * 16 + fm) * 32 + col8;

  const int nt = K >> 5;

#define STAGE(nb, k0)                                    \
  do {                                                   \
    unsigned short* L_ = lds + (nb) * TSZ;               \
    GLD16(gA0 + (k0), L_ + wb);                          \
    if (MI == 8) GLD16(gA1 + (k0), L_ + 4096 + wb);      \
    GLD16(gB0 + (k0), L_ + ASZ + wb);                    \
    GLD16(gB1 + (k0), L_ + ASZ + 4096 + wb);             \
  } while (0)

  // prologue: stage tiles 0 and 1 (K >= 64 always here)
  STAGE(0, 0);
  STAGE(1, 32);
  if (MI == 8) asm volatile("s_waitcnt vmcnt(4)" ::: "memory");
  else         asm volatile("s_waitcnt vmcnt(3)" ::: "memory");
  __builtin_amdgcn_s_barrier();

  for (int t = 0; t < nt; ++t) {
    const unsigned short* L = lds + (t & 1) * TSZ;
    // half 1: A-lo frags + all B frags, 4*MH MFMAs
    f16x8 af[MH], bf[4];
#pragma unroll
    for (int mi = 0; mi < MH; ++mi) af[mi] = *(const f16x8*)(L + aoff[mi]);
#pragma unroll
    for (int ni = 0; ni < 4; ++ni) bf[ni] = *(const f16x8*)(L + boff[ni]);
    __builtin_amdgcn_s_setprio(1);
#pragma unroll
    for (int mi = 0; mi < MH; ++mi)
#pragma unroll
      for (int ni = 0; ni < 4; ++ni)
        acc[mi][ni] = __builtin_amdgcn_mfma_f32_16x16x32_f16(af[mi], bf[ni],
                                                             acc[mi][ni], 0, 0, 0);
    __builtin_amdgcn_s_setprio(0);
    // half 2 reads, then declare this buffer fully read (barrier)
    f16x8 ag[MH];
#pragma unroll
    for (int mi = 0; mi < MH; ++mi) ag[mi] = *(const f16x8*)(L + aoff[MH + mi]);
    asm volatile("s_waitcnt lgkmcnt(0)" ::: "memory");
    __builtin_amdgcn_sched_barrier(0);
    __builtin_amdgcn_s_barrier();
    // refill the vacated buffer with tile t+2 while computing half 2
    if (t + 2 < nt) STAGE(t & 1, (t + 2) << 5);
    __builtin_amdgcn_s_setprio(1);
#pragma unroll
    for (int mi = 0; mi < MH; ++mi)
#pragma unroll
      for (int ni = 0; ni < 4; ++ni)
        acc[MH + mi][ni] = __builtin_amdgcn_mfma_f32_16x16x32_f16(ag[mi], bf[ni],
                                                                  acc[MH + mi][ni], 0, 0, 0);
    __builtin_amdgcn_s_setprio(0);
    // counted wait: tile t+1 landed, t+2's loads stay in flight
    if (t + 2 < nt) {
      if (MI == 8) asm volatile("s_waitcnt vmcnt(4)" ::: "memory");
      else         asm volatile("s_waitcnt vmcnt(3)" ::: "memory");
    } else if (t + 1 < nt) {
      asm volatile("s_waitcnt vmcnt(0)" ::: "memory");
    }
    __builtin_amdgcn_s_barrier();
  }
#undef STAGE

  // epilogue: C/D layout col=lane&15, row=(lane>>4)*4+reg
  const int cm = (lane >> 4) * 4;
  const int cn = lane & 15;
#pragma unroll
  for (int mi = 0; mi < MI; ++mi)
#pragma unroll
    for (int ni = 0; ni < 4; ++ni) {
#pragma unroll
      for (int r = 0; r < 4; ++r) {
        long long m = m0 + wr * (MI * 16) + mi * 16 + cm + r;
        long long n = n0 + wc * 64 + ni * 16 + cn;
        float v = acc[mi][ni][r] * scale;
        if (OUT_F16)
          ((unsigned short*)Cv)[(long long)bz * sC + m * N + n] = f2h(v);
        else
          ((float*)Cv)[(long long)bz * sC + m * N + n] = v;
      }
    }
}

// ---------------------------------------------------------------------------
// Wave-per-row sparsemax/softmax, element e = lane*32 + v.
// v5: NO LDS. Each lane loads its own 128B row chunk directly from global
// (all 64 lines per wave fully consumed from L1); epilogue re-reads the row
// through a laundered pointer (prevents CSE keeping 32 extra floats live).
// Swizzle batches are pinned with sched_barrier(0) so all 32 DS ops issue
// before any compare-exchange consumes them (counted lgkmcnt pipelining).
// LDS=0 + ~80 VGPR -> ~5 waves/SIMD instead of 2.8.
// ---------------------------------------------------------------------------
template <int K, int J>
__device__ __forceinline__ void intra_s(float (&r)[32]) {
#pragma unroll
  for (int v = 0; v < 32; ++v)
    if ((v & J) == 0) {
      const int u = v | J;
      const bool dsc = ((v & K) == 0);
      float a = r[v], b = r[u];
      float mx = fmaxf(a, b), mn = fminf(a, b);
      r[v] = dsc ? mx : mn;
      r[u] = dsc ? mn : mx;
    }
}

template <int J>
__device__ __forceinline__ void intra_desc(float (&r)[32]) {
#pragma unroll
  for (int v = 0; v < 32; ++v)
    if ((v & J) == 0) {
      const int u = v | J;
      float a = r[v], b = r[u];
      r[v] = fmaxf(a, b);
      r[u] = fminf(a, b);
    }
}

template <int JL>
__device__ __forceinline__ void cross_desc(float (&r)[32], int lane, int bp32) {
  const bool keepmax = ((lane & JL) == 0);
  float b[32];
#pragma unroll
  for (int v = 0; v < 32; ++v) {
    int av = __builtin_bit_cast(int, r[v]);
    int bv;
    if constexpr (JL == 32)
      bv = __builtin_amdgcn_ds_bpermute(bp32, av);
    else
      bv = __builtin_amdgcn_ds_swizzle(av, (JL << 10) | 0x1F);  // xor-mode swizzle
    b[v] = __builtin_bit_cast(float, bv);
  }
  __builtin_amdgcn_sched_barrier(0);   // pin: all swizzles issued before CEs
#pragma unroll
  for (int v = 0; v < 32; ++v) {
    float mx = fmaxf(r[v], b[v]), mn = fminf(r[v], b[v]);
    r[v] = keepmax ? mx : mn;
  }
}

__device__ __forceinline__ void signfix(float (&r)[32], unsigned fix) {
#pragma unroll
  for (int v = 0; v < 32; ++v)
    r[v] = __builtin_bit_cast(float, __builtin_bit_cast(unsigned, r[v]) ^ fix);
}

__global__ __launch_bounds__(256, 4) void attn_row_wave(const float* __restrict__ scores,
                                                        unsigned short* __restrict__ attn,
                                                        const float* __restrict__ absSum) {
  const int tid = threadIdx.x;
  const int lane = tid & 63;
  const int row = blockIdx.x * 4 + (tid >> 6);
  const float* rowp = scores + (long long)row * NROW;
  unsigned short* aout = attn + (long long)row * NROW;
  const int bp32 = (lane ^ 32) << 2;

  // per-lane contiguous 128B chunk: element e = lane*32 + v
  const float4* rp4 = (const float4*)rowp + lane * 8;
  float r[32];
  float lm = -INFINITY, lsraw = 0.f;
#pragma unroll
  for (int q = 0; q < 8; ++q) {
    float4 v = rp4[q];
    r[q * 4 + 0] = v.x; r[q * 4 + 1] = v.y;
    r[q * 4 + 2] = v.z; r[q * 4 + 3] = v.w;
    lm = fmaxf(lm, fmaxf(fmaxf(v.x, v.y), fmaxf(v.z, v.w)));
    lsraw += v.x + v.y + v.z + v.w;
  }
#pragma unroll
  for (int off = 32; off; off >>= 1) {
    lm = fmaxf(lm, __shfl_xor(lm, off, 64));
    lsraw += __shfl_xor(lsraw, off, 64);
  }

  const bool use_softmax = (absSum[0] * (1.0f / TOTX)) >= 1.0f;

  if (use_softmax) {
    float ls = 0.f;
#pragma unroll
    for (int v = 0; v < 32; ++v) { r[v] = expf(r[v] - lm); ls += r[v]; }
#pragma unroll
    for (int off = 32; off; off >>= 1) ls += __shfl_xor(ls, off, 64);
    float inv = 1.0f / ls;
    ushort4* op = (ushort4*)(aout + lane * 32);
#pragma unroll
    for (int q = 0; q < 8; ++q) {
      ushort4 o;
      o.x = f2h(r[q * 4 + 0] * inv); o.y = f2h(r[q * 4 + 1] * inv);
      o.z = f2h(r[q * 4 + 2] * inv); o.w = f2h(r[q * 4 + 3] * inv);
      op[q] = o;
    }
    return;
  }

  // ---- sparsemax ----
#pragma unroll
  for (int v = 0; v < 32; ++v) r[v] -= lm;
  const float step = ((lsraw - (float)NROW * lm) - 1.0f) * (1.0f / (float)NROW);

  // per-lane bitonic presort (compile-time directions)
  intra_s<2, 1>(r);
  intra_s<4, 2>(r); intra_s<4, 1>(r);
  intra_s<8, 4>(r); intra_s<8, 2>(r); intra_s<8, 1>(r);
  intra_s<16, 8>(r); intra_s<16, 4>(r); intra_s<16, 2>(r); intra_s<16, 1>(r);

  // merge ladder with running sign mask (negate-on-!dsc => all merges desc)
  unsigned cur = (unsigned)(lane & 1) << 31;               // kl=1
  signfix(r, cur);
  intra_desc<16>(r); intra_desc<8>(r); intra_desc<4>(r);
  intra_desc<2>(r); intra_desc<1>(r);

  { unsigned want = (unsigned)(lane & 2) << 30;            // kl=2
    signfix(r, cur ^ want); cur = want; }
  cross_desc<1>(r, lane, bp32);
  intra_desc<16>(r); intra_desc<8>(r); intra_desc<4>(r);
  intra_desc<2>(r); intra_desc<1>(r);

  { unsigned want = (unsigned)(lane & 4) << 29;            // kl=4
    signfix(r, cur ^ want); cur = want; }
  cross_desc<2>(r, lane, bp32); cross_desc<1>(r, lane, bp32);
  intra_desc<16>(r); intra_desc<8>(r); intra_desc<4>(r);
  intra_desc<2>(r); intra_desc<1>(r);

  { unsigned want = (unsigned)(lane & 8) << 28;            // kl=8
    signfix(r, cur ^ want); cur = want; }
  cross_desc<4>(r, lane, bp32); cross_desc<2>(r, lane, bp32);
  cross_desc<1>(r, lane, bp32);
  intra_desc<16>(r); intra_desc<8>(r); intra_desc<4>(r);
  intra_desc<2>(r); intra_desc<1>(r);

  { unsigned want = (unsigned)(lane & 16) << 27;           // kl=16
    signfix(r, cur ^ want); cur = want; }
  cross_desc<8>(r, lane, bp32); cross_desc<4>(r, lane, bp32);
  cross_desc<2>(r, lane, bp32); cross_desc<1>(r, lane, bp32);
  intra_desc<16>(r); intra_desc<8>(r); intra_desc<4>(r);
  intra_desc<2>(r); intra_desc<1>(r);

  { unsigned want = (unsigned)(lane & 32) << 26;           // kl=32
    signfix(r, cur ^ want); cur = want; }
  cross_desc<16>(r, lane, bp32); cross_desc<8>(r, lane, bp32);
  cross_desc<4>(r, lane, bp32); cross_desc<2>(r, lane, bp32);
  cross_desc<1>(r, lane, bp32);
  intra_desc<16>(r); intra_desc<8>(r); intra_desc<4>(r);
  intra_desc<2>(r); intra_desc<1>(r);

  signfix(r, cur);                                         // kl=64: dsc==true everywhere
  cross_desc<32>(r, lane, bp32); cross_desc<16>(r, lane, bp32);
  cross_desc<8>(r, lane, bp32); cross_desc<4>(r, lane, bp32);
  cross_desc<2>(r, lane, bp32); cross_desc<1>(r, lane, bp32);
  intra_desc<16>(r); intra_desc<8>(r); intra_desc<4>(r);
  intra_desc<2>(r); intra_desc<1>(r);

  // k = count(sorted > step)
  float lcnt = 0.f;
#pragma unroll
  for (int v = 0; v < 32; ++v) lcnt += (r[v] > step) ? 1.0f : 0.0f;
#pragma unroll
  for (int off = 32; off; off >>= 1) lcnt += __shfl_xor(lcnt, off, 64);
  const float kf = lcnt;

  // inclusive cumsum over e: local sequential + wave scan of lane totals
  float run = 0.f;
#pragma unroll
  for (int v = 0; v < 32; ++v) { run += r[v]; r[v] = run; }
  float pre = run;
#pragma unroll
  for (int off = 1; off < 64; off <<= 1) {
    float t = __shfl_up(pre, off, 64);
    if (lane >= off) pre += t;
  }
  pre -= run;  // exclusive prefix of lane totals
#pragma unroll
  for (int v = 0; v < 32; ++v) r[v] += pre;

  const float inv_k = 1.0f / kf;
  const float c1 = 1.0f + step * kf;

  // epilogue: re-read original z through a laundered pointer (blocks CSE of
  // the first-pass loads across the whole sort -> no 32-reg live range)
  unsigned long long up = (unsigned long long)rowp;
  asm volatile("" : "+v"(up));
  const float4* rp4e = (const float4*)up + lane * 8;
  ushort4* op = (ushort4*)(aout + lane * 32);
#pragma unroll
  for (int q = 0; q < 8; ++q) {
    float4 v = rp4e[q];
    ushort4 o;
    o.x = f2h(fmaxf((v.x - lm) - (r[q * 4 + 0] - c1) * inv_k, 0.0f));
    o.y = f2h(fmaxf((v.y - lm) - (r[q * 4 + 1] - c1) * inv_k, 0.0f));
    o.z = f2h(fmaxf((v.z - lm) - (r[q * 4 + 2] - c1) * inv_k, 0.0f));
    o.w = f2h(fmaxf((v.w - lm) - (r[q * 4 + 3] - c1) * inv_k, 0.0f));
    op[q] = o;
  }
}

// ---------------------------------------------------------------------------
extern "C" void kernel_launch(void* const* d_in, const int* in_sizes, int n_in,
                              void* d_out, int out_size, void* d_ws, size_t ws_size,
                              hipStream_t stream) {
  const float* x  = (const float*)d_in[0];
  const float* Wq = (const float*)d_in[1];
  const float* Wk = (const float*)d_in[2];
  const float* Wv = (const float*)d_in[3];
  float* out = (float*)d_out;

  const long long NX = (long long)B_ * S_ * D_;   // 8M
  const long long NW = (long long)H_ * D_;        // 1M

  // Workspace layout (total 144 MB + 4 B):
  //  [0,16MB):    x16          -> later Sc (fp32, 64MB, overwrites x16+W)
  //  [16,22MB):   Wq16 Wk16 Wv16 (contiguous, 2MB apart -> fused proj)
  //  [64,80MB):   Vt16 (persists to PV)
  //  [80,96MB):   Q16   [96,112MB): K16   [112,128MB): V16
  //               (contiguous 16MB apart -> fused proj output, sC = 8M elems)
  //  [80,112MB):  A16 (f16 attention, 32MB; overwrites Q16/K16 after scores)
  //  [144MB]:     flag
  char* base = (char*)d_ws;
  unsigned short* x16  = (unsigned short*)(base);
  unsigned short* Wq16 = (unsigned short*)(base + (16ll << 20));
  unsigned short* Wk16 = (unsigned short*)(base + (18ll << 20));
  unsigned short* Wv16 = (unsigned short*)(base + (20ll << 20));
  float*          Sc   = (float*)(base);
  unsigned short* Vt16 = (unsigned short*)(base + (64ll << 20));
  unsigned short* Q16  = (unsigned short*)(base + (80ll << 20));
  unsigned short* K16  = (unsigned short*)(base + (96ll << 20));
  unsigned short* V16  = (unsigned short*)(base + (112ll << 20));
  unsigned short* A16  = (unsigned short*)(base + (80ll << 20));
  float*          flag = (float*)(base + (144ll << 20));

  hipMemsetAsync(flag, 0, sizeof(float), stream);

  // fused x->f16 + abs-sum (grid-stride)
  f2h_abs_kernel<<<1024, 256, 0, stream>>>(x, x16, flag, (int)(NX / 4));
  // W -> f16, one launch
  f2h3_kernel<<<dim3((int)(NW / 4 + 255) / 256, 3), 256, 0, stream>>>(
      Wq, Wk, Wv, Wq16, Wk16, Wv16, (int)(NW / 4));

  // Projections fused: z selects W (stride 1M elems) and output (stride 8M elems)
  // MI=4 (128x256 tiles): 4 x 64 x 3 = 768 blocks -> 3 balanced rounds
  {
    dim3 grid(H_ / 256, (B_ * S_) / 128, 3);
    gemm8_nt<4, true><<<grid, 512, 0, stream>>>(x16, Wq16, Q16, B_ * S_, H_, D_,
                                                0, (long long)NW, (long long)(8ll << 20),
                                                1.0f);
  }

  // V^T per batch: [S][H] -> [H][S]
  {
    dim3 grid(H_ / 32, S_ / 32, B_);
    transpose_h16<<<grid, dim3(32, 8), 0, stream>>>(V16, Vt16, S_, H_);
  }

  // scores = Q @ K^T / 32 (batched, fp32 out; overwrites x16/W — all dead)
  // MI=8 (256x256): 8 x 8 x 4 = 256 blocks = exactly 1/CU
  {
    dim3 grid(S_ / 256, S_ / 256, B_);
    gemm8_nt<8, false><<<grid, 512, 0, stream>>>(Q16, K16, Sc, S_, S_, H_,
                                                 (long long)S_ * H_, (long long)S_ * H_,
                                                 (long long)S_ * S_, 1.0f / 32.0f);
  }

  // attention = sparsemax-or-softmax(scores) -> f16 (one wave per row)
  attn_row_wave<<<(B_ * S_) / 4, 256, 0, stream>>>(Sc, A16, flag);

  // out = attention @ Vt^T, f16 MFMA, fp32 out
  // MI=4 (128x256): 4 x 16 x 4 = 256 blocks (was 128 -> half machine idle)
  {
    dim3 grid(H_ / 256, S_ / 128, B_);
    gemm8_nt<4, false><<<grid, 512, 0, stream>>>(A16, Vt16, out, S_, H_, S_,
                                                 (long long)S_ * S_, (long long)H_ * S_,
                                                 (long long)S_ * H_, 1.0f);
  }
}